// Round 3
// baseline (1219.487 us; speedup 1.0000x reference)
//
#include <hip/hip_runtime.h>

typedef _Float16 f16x8 __attribute__((ext_vector_type(8)));
typedef _Float16 f16x4 __attribute__((ext_vector_type(4)));
typedef float f32x4 __attribute__((ext_vector_type(4)));

#define N_PIX 4096
#define C_IN  512
#define BN_INV 0.99999500003749969f  // 1/sqrt(1+1e-5)

__device__ __forceinline__ f32x4 mfma16(f16x8 a, f16x8 b, f32x4 c) {
  return __builtin_amdgcn_mfma_f32_16x16x32_f16(a, b, c, 0, 0, 0);
}
// NT fragment load: row = base_row + (lane&15), 8 contiguous k at k0 + (lane>>4)*8
__device__ __forceinline__ f16x8 ldnt(const _Float16* base, int row, int ld, int k0, int lane) {
  return *(const f16x8*)(base + (size_t)(row + (lane & 15)) * ld + k0 + ((lane >> 4) << 3));
}

// ---------- x NCHW fp32 -> xT [b][pix][c] fp16 (LDS tile transpose) ----------
__global__ __launch_bounds__(256) void k_xT(const float* __restrict__ x, _Float16* __restrict__ xT) {
  __shared__ float t[32][33];
  int b = blockIdx.z, p0 = blockIdx.x * 32, c0 = blockIdx.y * 32;
  int tx = threadIdx.x & 31, ty = threadIdx.x >> 5;  // 32 x 8
  const float* xb = x + ((size_t)b * C_IN + c0) * N_PIX + p0;
  for (int i = 0; i < 32; i += 8) t[ty + i][tx] = xb[(size_t)(ty + i) * N_PIX + tx];
  __syncthreads();
  _Float16* o = xT + ((size_t)b * N_PIX + p0) * C_IN + c0;
  for (int i = 0; i < 32; i += 8) o[(size_t)(ty + i) * C_IN + tx] = (_Float16)t[tx][ty + i];
}

// ---------- fused fp32 -> fp16 for 4 weight tensors ----------
__global__ __launch_bounds__(256) void k_f2h4(const float* __restrict__ a, _Float16* __restrict__ oa, int na,
                                              const float* __restrict__ b_, _Float16* __restrict__ ob, int nb,
                                              const float* __restrict__ c, _Float16* __restrict__ oc, int nc,
                                              const float* __restrict__ d, _Float16* __restrict__ od, int nd) {
  int i = blockIdx.x * 256 + threadIdx.x;
  if (i < na) { oa[i] = (_Float16)a[i]; return; }
  i -= na;
  if (i < nb) { ob[i] = (_Float16)b_[i]; return; }
  i -= nb;
  if (i < nc) { oc[i] = (_Float16)c[i]; return; }
  i -= nc;
  if (i < nd) od[i] = (_Float16)d[i];
}

// ---------- pack 3x3 dilated conv weights: [conv][tap][oc][c] fp16 ----------
__global__ __launch_bounds__(256) void k_packw(const float* __restrict__ w2, const float* __restrict__ w3,
                                               const float* __restrict__ w4, _Float16* __restrict__ wp) {
  int idx = blockIdx.x * 256 + threadIdx.x;  // 3*9*128*512 = 1769472
  int conv = idx / 589824;
  int t1 = idx % 589824;
  int tap = t1 / 65536;
  int t2 = t1 % 65536;
  int oc = t2 / 512, c = t2 % 512;
  const float* w = (conv == 0) ? w2 : (conv == 1) ? w3 : w4;
  wp[idx] = (_Float16)w[(size_t)(oc * 512 + c) * 9 + tap];
}

// ---------- per (b,c) mean over pixels ----------
__global__ __launch_bounds__(256) void k_mean(const float* __restrict__ x, float* __restrict__ meanv) {
  int c = blockIdx.x, b = blockIdx.y;
  const float* p = x + ((size_t)b * C_IN + c) * N_PIX;
  float s = 0.f;
  for (int i = threadIdx.x; i < N_PIX; i += 256) s += p[i];
  for (int off = 32; off; off >>= 1) s += __shfl_down(s, off);
  __shared__ float ls[4];
  if ((threadIdx.x & 63) == 0) ls[threadIdx.x >> 6] = s;
  __syncthreads();
  if (threadIdx.x == 0) meanv[(size_t)b * C_IN + c] = (ls[0] + ls[1] + ls[2] + ls[3]) * (1.f / N_PIX);
}

// ---------- branch 5: 1x1 conv on pooled vector + BN + ReLU ----------
__global__ void k_p5(const float* __restrict__ w5, const float* __restrict__ meanv,
                     const float* __restrict__ bnS, const float* __restrict__ bnB, _Float16* __restrict__ p5h) {
  int b = blockIdx.x, oc = threadIdx.x;  // 128 threads
  const float* m = meanv + (size_t)b * C_IN;
  const float* w = w5 + (size_t)oc * C_IN;
  float s = 0.f;
  for (int c = 0; c < C_IN; ++c) s += w[c] * m[c];
  float v = fmaxf(s * bnS[oc] * BN_INV + bnB[oc], 0.f);
  p5h[b * 128 + oc] = (_Float16)v;
}

// ---------- broadcast b5 into featT channels [512,640) ----------
__global__ __launch_bounds__(256) void k_b5(const _Float16* __restrict__ p5h, _Float16* __restrict__ featT) {
  int i = blockIdx.x * 256 + threadIdx.x;  // 4*4096*128
  int oc = i & 127, p = (i >> 7) & 4095, b = i >> 19;
  featT[((size_t)b * N_PIX + p) * 640 + 512 + oc] = p5h[b * 128 + oc];
}

// ---------- unified ASPP conv kernel: task 0 = 1x1, tasks 1..3 = dilated 3x3 ----------
// grid (64 p-tiles, 2 oc-halves, 4 tasks * 4 batches)
__global__ __launch_bounds__(256) void k_conv(const _Float16* __restrict__ xT, const _Float16* __restrict__ w1h,
                                              const _Float16* __restrict__ wph, const float* __restrict__ bnS,
                                              const float* __restrict__ bnB, _Float16* __restrict__ featT) {
  int task = blockIdx.z >> 2, b = blockIdx.z & 3;
  int p0 = blockIdx.x * 64, ocOff = blockIdx.y * 64;
  int tid = threadIdx.x, wid = tid >> 6, lane = tid & 63;
  const _Float16* A = xT + (size_t)b * N_PIX * C_IN;
  int pr = p0 + wid * 16;
  int p = pr + (lane & 15);
  int y = p >> 6, xx = p & 63;
  int dil = (task == 1) ? 2 : (task == 2) ? 3 : 6;
  int ntap = (task == 0) ? 1 : 9;
  f32x4 acc[4] = {};
  for (int tap = 0; tap < ntap; ++tap) {
    int dy, dx;
    const _Float16* wt;
    if (task == 0) {
      dy = 0; dx = 0; wt = w1h;
    } else {
      dy = (tap / 3 - 1) * dil;
      dx = (tap % 3 - 1) * dil;
      wt = wph + (size_t)((task - 1) * 9 + tap) * (128 * C_IN);
    }
    int py = y + dy, px = xx + dx;
    bool valid = ((unsigned)py < 64u) && ((unsigned)px < 64u);
    const _Float16* Arow = A + (size_t)(p + dy * 64 + dx) * C_IN + ((lane >> 4) << 3);
    for (int kk = 0; kk < 16; ++kk) {
      f16x8 af = {};
      if (valid) af = *(const f16x8*)(Arow + kk * 32);
#pragma unroll
      for (int nn = 0; nn < 4; ++nn) {
        f16x8 bf = ldnt(wt, ocOff + nn * 16, C_IN, kk * 32, lane);
        acc[nn] = mfma16(af, bf, acc[nn]);
      }
    }
  }
  _Float16* F = featT + (size_t)b * N_PIX * 640;
  int brOff = task * 128;
#pragma unroll
  for (int nn = 0; nn < 4; ++nn) {
    int oc = ocOff + nn * 16 + (lane & 15);
    float inv = bnS[brOff + oc] * BN_INV, bs = bnB[brOff + oc];
#pragma unroll
    for (int r = 0; r < 4; ++r) {
      int pix = pr + ((lane >> 4) << 2) + r;
      F[(size_t)pix * 640 + brOff + oc] = (_Float16)fmaxf(acc[nn][r] * inv + bs, 0.f);
    }
  }
}

// ---------- q & k in one dispatch: 1x1 conv 640->128 + bias -> [b][pix][128] fp16 ----------
// grid (64 p-tiles, 2 which, 4 b)
__global__ __launch_bounds__(256) void k_qk(const _Float16* __restrict__ featT, const _Float16* __restrict__ wqh,
                                            const _Float16* __restrict__ wkh, const float* __restrict__ bq,
                                            const float* __restrict__ bk, _Float16* __restrict__ qT,
                                            _Float16* __restrict__ kT) {
  int b = blockIdx.z, which = blockIdx.y, p0 = blockIdx.x * 64;
  const _Float16* wh = which ? wkh : wqh;
  const float* bias = which ? bk : bq;
  _Float16* oT = which ? kT : qT;
  int tid = threadIdx.x, wid = tid >> 6, lane = tid & 63;
  const _Float16* A = featT + (size_t)b * N_PIX * 640;
  int pr = p0 + wid * 16;
  f32x4 acc[8] = {};
  for (int kk = 0; kk < 20; ++kk) {
    f16x8 af = ldnt(A, pr, 640, kk * 32, lane);
#pragma unroll
    for (int nn = 0; nn < 8; ++nn) {
      f16x8 bf = ldnt(wh, nn * 16, 640, kk * 32, lane);
      acc[nn] = mfma16(af, bf, acc[nn]);
    }
  }
  _Float16* O = oT + (size_t)b * N_PIX * 128;
#pragma unroll
  for (int nn = 0; nn < 8; ++nn) {
    int oc = nn * 16 + (lane & 15);
    float bb = bias[oc];
#pragma unroll
    for (int r = 0; r < 4; ++r) {
      int pix = pr + ((lane >> 4) << 2) + r;
      O[(size_t)pix * 128 + oc] = (_Float16)(acc[nn][r] + bb);
    }
  }
}

// ---------- v: 1x1 conv 512->512 + bias -> [b][c][pix] fp16 (channel-major) ----------
__global__ __launch_bounds__(256) void k_v(const _Float16* __restrict__ xT, const _Float16* __restrict__ wvh,
                                           const float* __restrict__ bv, _Float16* __restrict__ vv) {
  int b = blockIdx.z, oc0 = blockIdx.x * 64, p0 = blockIdx.y * 128;
  int tid = threadIdx.x, wid = tid >> 6, lane = tid & 63;
  const _Float16* Bm = xT + (size_t)b * N_PIX * C_IN;
  int or0 = oc0 + wid * 16;
  f32x4 acc[8] = {};
  for (int kk = 0; kk < 16; ++kk) {
    f16x8 af = ldnt(wvh, or0, C_IN, kk * 32, lane);
#pragma unroll
    for (int nn = 0; nn < 8; ++nn) {
      f16x8 bf = ldnt(Bm, p0 + nn * 16, C_IN, kk * 32, lane);
      acc[nn] = mfma16(af, bf, acc[nn]);
    }
  }
  _Float16* V = vv + (size_t)b * C_IN * N_PIX;
#pragma unroll
  for (int r = 0; r < 4; ++r) {
    int oc = or0 + ((lane >> 4) << 2) + r;
    float bb = bv[oc];
#pragma unroll
    for (int nn = 0; nn < 8; ++nn) {
      int pix = p0 + nn * 16 + (lane & 15);
      V[(size_t)oc * N_PIX + pix] = (_Float16)(acc[nn][r] + bb);
    }
  }
}

// ---------- pass 1: partial row max + sumexp over an m-eighth (S^T orientation) ----------
__global__ __launch_bounds__(256) void k_pass1(const _Float16* __restrict__ qT, const _Float16* __restrict__ kT,
                                               float* __restrict__ pmaxP, float* __restrict__ psumP) {
  int b = blockIdx.z, n0 = blockIdx.x * 64, mq = blockIdx.y;
  int tid = threadIdx.x, wid = tid >> 6, lane = tid & 63;
  const _Float16* Q = qT + (size_t)b * N_PIX * 128;
  const _Float16* K = kT + (size_t)b * N_PIX * 128;
  f16x8 qf[4];
#pragma unroll
  for (int kk = 0; kk < 4; ++kk) qf[kk] = ldnt(Q, n0 + wid * 16, 128, kk * 32, lane);
  float mx = -3.4e38f, sm = 0.f;
  for (int it = 0; it < 8; ++it) {
    int m0 = mq * 512 + it * 64;
#pragma unroll
    for (int mm = 0; mm < 4; ++mm) {
      f32x4 s = {};
#pragma unroll
      for (int kk = 0; kk < 4; ++kk) {
        f16x8 kf = ldnt(K, m0 + mm * 16, 128, kk * 32, lane);
        s = mfma16(kf, qf[kk], s);  // S^T: col = n (lane&15), rows = m
      }
      float vmax = fmaxf(fmaxf(s[0], s[1]), fmaxf(s[2], s[3]));
      float newm = fmaxf(mx, vmax);
      sm = sm * __expf(mx - newm) + __expf(s[0] - newm) + __expf(s[1] - newm) +
           __expf(s[2] - newm) + __expf(s[3] - newm);
      mx = newm;
    }
  }
  // combine lanes holding the same n (lane, lane^16, lane^32)
#pragma unroll
  for (int off = 16; off < 64; off <<= 1) {
    float mo = __shfl_xor(mx, off);
    float lo = __shfl_xor(sm, off);
    float mn = fmaxf(mx, mo);
    sm = sm * __expf(mx - mn) + lo * __expf(mo - mn);
    mx = mn;
  }
  if (lane < 16) {
    size_t idx = ((size_t)(b * 8 + mq)) * N_PIX + n0 + wid * 16 + lane;
    pmaxP[idx] = mx;
    psumP[idx] = sm;
  }
}

// ---------- combine 8 m-eighth partials -> rmax, rsum ----------
__global__ __launch_bounds__(256) void k_comb(const float* __restrict__ pmaxP, const float* __restrict__ psumP,
                                              float* __restrict__ rmax, float* __restrict__ rsum) {
  int i = blockIdx.x * 256 + threadIdx.x;  // 4*4096
  int b = i >> 12, n = i & 4095;
  float m = -3.4e38f, l = 0.f;
#pragma unroll
  for (int q = 0; q < 8; ++q) {
    size_t idx = ((size_t)(b * 8 + q)) * N_PIX + n;
    float mq = pmaxP[idx], lq = psumP[idx];
    float nm = fmaxf(m, mq);
    l = l * __expf(m - nm) + lq * __expf(mq - nm);
    m = nm;
  }
  rmax[(size_t)b * N_PIX + n] = m;
  rsum[(size_t)b * N_PIX + n] = l;
}

// ---------- pass 2: fused S^T recompute -> P -> PV -> y = x + gamma*O/sum ----------
// n-tile 32, m-tile 128/barrier, c-split 2, XOR-swizzled double-buffered P.
// grid (128 n-tiles, 2 c, 4 b) = 1024 blocks = 4/CU; launch_bounds caps VGPR at 128.
__global__ __launch_bounds__(256, 4) void k_pass2(const _Float16* __restrict__ qT, const _Float16* __restrict__ kT,
                                                  const _Float16* __restrict__ vv, const float* __restrict__ rmax,
                                                  const float* __restrict__ rsum, const float* __restrict__ x,
                                                  const float* __restrict__ gamma, float* __restrict__ out) {
  __shared__ _Float16 Pb[2][32 * 128];  // [buf][n][m], row = 256B, XOR-swizzled by (n&7)<<4
  int b = blockIdx.z, n0 = blockIdx.x * 32, c0 = blockIdx.y * 256;
  int tid = threadIdx.x, wid = tid >> 6, lane = tid & 63;
  int ns = wid & 1;   // phaseA n-sub (16 rows)
  int wm = wid >> 1;  // phaseA m-half (64 of 128)
  const _Float16* Q = qT + (size_t)b * N_PIX * 128;
  const _Float16* K = kT + (size_t)b * N_PIX * 128;
  const _Float16* V = vv + (size_t)b * C_IN * N_PIX;
  float g = gamma[0];
  f16x8 qf[4];
#pragma unroll
  for (int kk = 0; kk < 4; ++kk) qf[kk] = ldnt(Q, n0 + ns * 16, 128, kk * 32, lane);
  int n_local = ns * 16 + (lane & 15);
  float pmax = rmax[(size_t)b * N_PIX + n0 + n_local];
  f32x4 acc[4][2] = {};

  auto phaseA = [&](int it, int buf) {
    int m_base = it * 128 + wm * 64;
#pragma unroll
    for (int mm = 0; mm < 4; ++mm) {
      f32x4 s = {};
#pragma unroll
      for (int kk = 0; kk < 4; ++kk) {
        f16x8 kf = ldnt(K, m_base + mm * 16, 128, kk * 32, lane);
        s = mfma16(kf, qf[kk], s);  // S^T: col=n, rows=m
      }
      f16x4 pv;
#pragma unroll
      for (int r = 0; r < 4; ++r) pv[r] = (_Float16)__expf(s[r] - pmax);
      int m_local = wm * 64 + mm * 16 + ((lane >> 4) << 2);
      int mb = (m_local * 2) ^ ((n_local & 7) << 4);
      *(f16x4*)((char*)&Pb[buf][0] + n_local * 256 + mb) = pv;
    }
  };
  auto phaseB = [&](int it, int buf) {
#pragma unroll
    for (int k2 = 0; k2 < 4; ++k2) {
      int mb = (k2 * 64 + ((lane >> 4) << 4)) ^ ((lane & 7) << 4);
      f16x8 pb0 = *(const f16x8*)((char*)&Pb[buf][0] + (lane & 15) * 256 + mb);
      f16x8 pb1 = *(const f16x8*)((char*)&Pb[buf][0] + (16 + (lane & 15)) * 256 + mb);
#pragma unroll
      for (int cc = 0; cc < 4; ++cc) {
        f16x8 af = ldnt(V, c0 + wid * 64 + cc * 16, N_PIX, it * 128 + k2 * 32, lane);
        acc[cc][0] = mfma16(af, pb0, acc[cc][0]);
        acc[cc][1] = mfma16(af, pb1, acc[cc][1]);
      }
    }
  };

  phaseA(0, 0);
  __syncthreads();
  for (int it = 0; it < 31; ++it) {
    phaseA(it + 1, (it + 1) & 1);  // fill other buffer
    phaseB(it, it & 1);            // consume current buffer
    __syncthreads();
  }
  phaseB(31, 1);

  // epilogue: normalize by row sum, y = x + g*O
  float inv_s[2];
#pragma unroll
  for (int n2 = 0; n2 < 2; ++n2)
    inv_s[n2] = 1.f / rsum[(size_t)b * N_PIX + n0 + n2 * 16 + (lane & 15)];
#pragma unroll
  for (int cc = 0; cc < 4; ++cc) {
#pragma unroll
    for (int r = 0; r < 4; ++r) {
      int oc = c0 + wid * 64 + cc * 16 + ((lane >> 4) << 2) + r;
#pragma unroll
      for (int n2 = 0; n2 < 2; ++n2) {
        int pix = n0 + n2 * 16 + (lane & 15);
        size_t idx = ((size_t)(b * C_IN + oc)) * N_PIX + pix;
        out[idx] = fmaf(g * inv_s[n2], acc[cc][n2][r], x[idx]);
      }
    }
  }
}

extern "C" void kernel_launch(void* const* d_in, const int* in_sizes, int n_in,
                              void* d_out, int out_size, void* d_ws, size_t ws_size,
                              hipStream_t stream) {
  const float* x = (const float*)d_in[0];
  const float* wa1 = (const float*)d_in[1];
  const float* wa2 = (const float*)d_in[2];
  const float* wa3 = (const float*)d_in[3];
  const float* wa4 = (const float*)d_in[4];
  const float* wa5 = (const float*)d_in[5];
  const float* bnS = (const float*)d_in[6];
  const float* bnB = (const float*)d_in[7];
  const float* wq = (const float*)d_in[8];
  const float* bq = (const float*)d_in[9];
  const float* wk = (const float*)d_in[10];
  const float* bk = (const float*)d_in[11];
  const float* wv = (const float*)d_in[12];
  const float* bv = (const float*)d_in[13];
  const float* gamma = (const float*)d_in[14];

  char* ws = (char*)d_ws;
  size_t off = 0;
  auto alloc = [&](size_t bytes) -> char* {
    char* p = ws + off;
    off = (off + bytes + 255) & ~(size_t)255;
    return p;
  };
  _Float16* xT = (_Float16*)alloc((size_t)4 * 4096 * 512 * 2);
  _Float16* featT = (_Float16*)alloc((size_t)4 * 4096 * 640 * 2);
  _Float16* qT = (_Float16*)alloc((size_t)4 * 4096 * 128 * 2);
  _Float16* kT = (_Float16*)alloc((size_t)4 * 4096 * 128 * 2);
  _Float16* vvp = (_Float16*)alloc((size_t)4 * 512 * 4096 * 2);
  _Float16* w1h = (_Float16*)alloc((size_t)128 * 512 * 2);
  _Float16* wph = (_Float16*)alloc((size_t)3 * 9 * 128 * 512 * 2);
  _Float16* wqh = (_Float16*)alloc((size_t)128 * 640 * 2);
  _Float16* wkh = (_Float16*)alloc((size_t)128 * 640 * 2);
  _Float16* wvh = (_Float16*)alloc((size_t)512 * 512 * 2);
  float* meanv = (float*)alloc((size_t)4 * 512 * 4);
  _Float16* p5h = (_Float16*)alloc((size_t)4 * 128 * 2);
  float* rmax = (float*)alloc((size_t)4 * 4096 * 4);
  float* rsum = (float*)alloc((size_t)4 * 4096 * 4);
  float* pmaxP = (float*)alloc((size_t)4 * 8 * 4096 * 4);
  float* psumP = (float*)alloc((size_t)4 * 8 * 4096 * 4);
  if (off > ws_size) return;  // workspace too small -> fail loudly via wrong output

  float* out = (float*)d_out;

  // stage inputs
  hipLaunchKernelGGL(k_xT, dim3(128, 16, 4), dim3(256), 0, stream, x, xT);
  hipLaunchKernelGGL(k_f2h4, dim3(1920), dim3(256), 0, stream, wa1, w1h, 65536, wq, wqh, 81920, wk, wkh, 81920,
                     wv, wvh, 262144);
  hipLaunchKernelGGL(k_packw, dim3(6912), dim3(256), 0, stream, wa2, wa3, wa4, wph);
  // ASPP
  hipLaunchKernelGGL(k_mean, dim3(512, 4), dim3(256), 0, stream, x, meanv);
  hipLaunchKernelGGL(k_p5, dim3(4), dim3(128), 0, stream, wa5, meanv, bnS + 4 * 128, bnB + 4 * 128, p5h);
  hipLaunchKernelGGL(k_b5, dim3(8192), dim3(256), 0, stream, p5h, featT);
  hipLaunchKernelGGL(k_conv, dim3(64, 2, 16), dim3(256), 0, stream, xT, w1h, wph, bnS, bnB, featT);
  // q, k, v
  hipLaunchKernelGGL(k_qk, dim3(64, 2, 4), dim3(256), 0, stream, featT, wqh, wkh, bq, bk, qT, kT);
  hipLaunchKernelGGL(k_v, dim3(8, 32, 4), dim3(256), 0, stream, xT, wvh, bv, vvp);
  // attention
  hipLaunchKernelGGL(k_pass1, dim3(64, 8, 4), dim3(256), 0, stream, qT, kT, pmaxP, psumP);
  hipLaunchKernelGGL(k_comb, dim3(64), dim3(256), 0, stream, pmaxP, psumP, rmax, rsum);
  hipLaunchKernelGGL(k_pass2, dim3(128, 2, 4), dim3(256), 0, stream, qT, kT, vvp, rmax, rsum, x, gamma, out);
}

// Round 4
// 847.490 us; speedup vs baseline: 1.4389x; 1.4389x over previous
//
#include <hip/hip_runtime.h>

typedef _Float16 f16x8 __attribute__((ext_vector_type(8)));
typedef _Float16 f16x4 __attribute__((ext_vector_type(4)));
typedef float f32x4 __attribute__((ext_vector_type(4)));

#define N_PIX 4096
#define C_IN  512
#define BN_INV 0.99999500003749969f  // 1/sqrt(1+1e-5)
#define CCH 64  // conv c-chunk (K per LDS stage)

__device__ __forceinline__ f32x4 mfma16(f16x8 a, f16x8 b, f32x4 c) {
  return __builtin_amdgcn_mfma_f32_16x16x32_f16(a, b, c, 0, 0, 0);
}
// NT fragment load: row = base_row + (lane&15), 8 contiguous k at k0 + (lane>>4)*8
__device__ __forceinline__ f16x8 ldnt(const _Float16* base, int row, int ld, int k0, int lane) {
  return *(const f16x8*)(base + (size_t)(row + (lane & 15)) * ld + k0 + ((lane >> 4) << 3));
}

// ---------- x NCHW fp32 -> xT [b][pix][c] fp16 (LDS tile transpose) ----------
__global__ __launch_bounds__(256) void k_xT(const float* __restrict__ x, _Float16* __restrict__ xT) {
  __shared__ float t[32][33];
  int b = blockIdx.z, p0 = blockIdx.x * 32, c0 = blockIdx.y * 32;
  int tx = threadIdx.x & 31, ty = threadIdx.x >> 5;  // 32 x 8
  const float* xb = x + ((size_t)b * C_IN + c0) * N_PIX + p0;
  for (int i = 0; i < 32; i += 8) t[ty + i][tx] = xb[(size_t)(ty + i) * N_PIX + tx];
  __syncthreads();
  _Float16* o = xT + ((size_t)b * N_PIX + p0) * C_IN + c0;
  for (int i = 0; i < 32; i += 8) o[(size_t)(ty + i) * C_IN + tx] = (_Float16)t[tx][ty + i];
}

// ---------- fused fp32 -> fp16 for 4 weight tensors ----------
__global__ __launch_bounds__(256) void k_f2h4(const float* __restrict__ a, _Float16* __restrict__ oa, int na,
                                              const float* __restrict__ b_, _Float16* __restrict__ ob, int nb,
                                              const float* __restrict__ c, _Float16* __restrict__ oc, int nc,
                                              const float* __restrict__ d, _Float16* __restrict__ od, int nd) {
  int i = blockIdx.x * 256 + threadIdx.x;
  if (i < na) { oa[i] = (_Float16)a[i]; return; }
  i -= na;
  if (i < nb) { ob[i] = (_Float16)b_[i]; return; }
  i -= nb;
  if (i < nc) { oc[i] = (_Float16)c[i]; return; }
  i -= nc;
  if (i < nd) od[i] = (_Float16)d[i];
}

// ---------- pack 3x3 dilated conv weights: [conv][tap][oc][c] fp16 ----------
__global__ __launch_bounds__(256) void k_packw(const float* __restrict__ w2, const float* __restrict__ w3,
                                               const float* __restrict__ w4, _Float16* __restrict__ wp) {
  int idx = blockIdx.x * 256 + threadIdx.x;  // 3*9*128*512 = 1769472
  int conv = idx / 589824;
  int t1 = idx % 589824;
  int tap = t1 / 65536;
  int t2 = t1 % 65536;
  int oc = t2 / 512, c = t2 % 512;
  const float* w = (conv == 0) ? w2 : (conv == 1) ? w3 : w4;
  wp[idx] = (_Float16)w[(size_t)(oc * 512 + c) * 9 + tap];
}

// ---------- per (b,c) mean over pixels ----------
__global__ __launch_bounds__(256) void k_mean(const float* __restrict__ x, float* __restrict__ meanv) {
  int c = blockIdx.x, b = blockIdx.y;
  const float* p = x + ((size_t)b * C_IN + c) * N_PIX;
  float s = 0.f;
  for (int i = threadIdx.x; i < N_PIX; i += 256) s += p[i];
  for (int off = 32; off; off >>= 1) s += __shfl_down(s, off);
  __shared__ float ls[4];
  if ((threadIdx.x & 63) == 0) ls[threadIdx.x >> 6] = s;
  __syncthreads();
  if (threadIdx.x == 0) meanv[(size_t)b * C_IN + c] = (ls[0] + ls[1] + ls[2] + ls[3]) * (1.f / N_PIX);
}

// ---------- branch 5: 1x1 conv on pooled vector + BN + ReLU ----------
__global__ void k_p5(const float* __restrict__ w5, const float* __restrict__ meanv,
                     const float* __restrict__ bnS, const float* __restrict__ bnB, _Float16* __restrict__ p5h) {
  int b = blockIdx.x, oc = threadIdx.x;  // 128 threads
  const float* m = meanv + (size_t)b * C_IN;
  const float* w = w5 + (size_t)oc * C_IN;
  float s = 0.f;
  for (int c = 0; c < C_IN; ++c) s += w[c] * m[c];
  float v = fmaxf(s * bnS[oc] * BN_INV + bnB[oc], 0.f);
  p5h[b * 128 + oc] = (_Float16)v;
}

// ---------- broadcast b5 into featT channels [512,640) ----------
__global__ __launch_bounds__(256) void k_b5(const _Float16* __restrict__ p5h, _Float16* __restrict__ featT) {
  int i = blockIdx.x * 256 + threadIdx.x;  // 4*4096*128
  int oc = i & 127, p = (i >> 7) & 4095, b = i >> 19;
  featT[((size_t)b * N_PIX + p) * 640 + 512 + oc] = p5h[b * 128 + oc];
}

// ---------- unified ASPP conv: LDS-staged implicit GEMM ----------
// Block = one output image row (64 px) x all 128 oc, for one (task, b).
// Taps for dilation d read only rows {y-d, y, y+d}: stage them per c-chunk in LDS,
// zero-padded +-6 columns, XOR-swizzled (col&7)<<4 for conflict-free ds_read_b128.
// grid (64 rows, 16 task*b); task 0 = 1x1 conv (1 tap, 1 row).
__global__ __launch_bounds__(256, 4) void k_conv(const _Float16* __restrict__ xT, const _Float16* __restrict__ w1h,
                                                 const _Float16* __restrict__ wph, const float* __restrict__ bnS,
                                                 const float* __restrict__ bnB, _Float16* __restrict__ featT) {
  __shared__ _Float16 Ap[3 * 76 * CCH];  // 29184 B
  int y = blockIdx.x;
  int tb = blockIdx.y;
  int task = tb >> 2, b = tb & 3;
  int tid = threadIdx.x, wid = tid >> 6, lane = tid & 63;
  int dil = (task == 0) ? 0 : (task == 1) ? 2 : (task == 2) ? 3 : 6;
  int ntap = task ? 9 : 1;
  int nrow = task ? 3 : 1;
  const _Float16* wt0 = task ? wph + (size_t)(task - 1) * 9 * 128 * C_IN : w1h;
  f32x4 acc[4][2] = {};

  for (int cc = 0; cc < C_IN / CCH; ++cc) {
    int c0 = cc * CCH;
    __syncthreads();  // previous chunk's compute done reading LDS
    // zero the +-dil column borders (disjoint from fill region)
    if (dil) {
      int nz = nrow * 2 * dil * (CCH / 8);
      for (int i = tid; i < nz; i += 256) {
        int cv = (i & (CCH / 8 - 1)) * 8;
        int t2 = i / (CCH / 8);
        int colh = t2 % (2 * dil);
        int r = t2 / (2 * dil);
        int col = (colh < dil) ? colh : 64 + colh;  // [0,dil) U [64+dil, 64+2dil)
        int ba = (((r * 76 + col) * CCH + cv) * 2) ^ ((col & 7) << 4);
        *(f16x8*)((char*)Ap + ba) = (f16x8){};
      }
    }
    // fill rows y + (r-1)*dil (zeros when off-image)
    int nf = nrow * 64 * (CCH / 8);
    for (int i = tid; i < nf; i += 256) {
      int cv = (i & (CCH / 8 - 1)) * 8;
      int t2 = i / (CCH / 8);
      int px = t2 & 63;
      int r = t2 >> 6;
      int ry = y + (r - 1) * dil;
      f16x8 v = {};
      if ((unsigned)ry < 64u)
        v = *(const f16x8*)(xT + ((size_t)b * N_PIX + ry * 64 + px) * C_IN + c0 + cv);
      int col = dil + px;
      int ba = (((r * 76 + col) * CCH + cv) * 2) ^ ((col & 7) << 4);
      *(f16x8*)((char*)Ap + ba) = v;
    }
    __syncthreads();
    // compute: each wave owns 32 oc
    for (int tap = 0; tap < ntap; ++tap) {
      int rsel = tap / 3;
      int dx = (tap % 3 - 1) * dil;
      const _Float16* wt = wt0 + (size_t)tap * 128 * C_IN;
#pragma unroll
      for (int k = 0; k < CCH / 32; ++k) {
        f16x8 wf0 = ldnt(wt, wid * 32, C_IN, c0 + k * 32, lane);
        f16x8 wf1 = ldnt(wt, wid * 32 + 16, C_IN, c0 + k * 32, lane);
        f16x8 af[4];
#pragma unroll
        for (int m = 0; m < 4; ++m) {
          int col = dil + dx + m * 16 + (lane & 15);
          int ch = k * 32 + ((lane >> 4) << 3);
          int ba = (((rsel * 76 + col) * CCH + ch) * 2) ^ ((col & 7) << 4);
          af[m] = *(const f16x8*)((char*)Ap + ba);
        }
#pragma unroll
        for (int m = 0; m < 4; ++m) {
          acc[m][0] = mfma16(af[m], wf0, acc[m][0]);
          acc[m][1] = mfma16(af[m], wf1, acc[m][1]);
        }
      }
    }
  }
  // epilogue: BN + ReLU -> featT
  int brOff = task * 128;
  _Float16* F = featT + (size_t)b * N_PIX * 640;
#pragma unroll
  for (int n = 0; n < 2; ++n) {
    int oc = wid * 32 + n * 16 + (lane & 15);
    float inv = bnS[brOff + oc] * BN_INV, bs = bnB[brOff + oc];
#pragma unroll
    for (int m = 0; m < 4; ++m) {
#pragma unroll
      for (int r = 0; r < 4; ++r) {
        int pix = y * 64 + m * 16 + ((lane >> 4) << 2) + r;
        F[(size_t)pix * 640 + brOff + oc] = (_Float16)fmaxf(acc[m][n][r] * inv + bs, 0.f);
      }
    }
  }
}

// ---------- q & k in one dispatch: 1x1 conv 640->128 + bias -> [b][pix][128] fp16 ----------
__global__ __launch_bounds__(256) void k_qk(const _Float16* __restrict__ featT, const _Float16* __restrict__ wqh,
                                            const _Float16* __restrict__ wkh, const float* __restrict__ bq,
                                            const float* __restrict__ bk, _Float16* __restrict__ qT,
                                            _Float16* __restrict__ kT) {
  int b = blockIdx.z, which = blockIdx.y, p0 = blockIdx.x * 64;
  const _Float16* wh = which ? wkh : wqh;
  const float* bias = which ? bk : bq;
  _Float16* oT = which ? kT : qT;
  int tid = threadIdx.x, wid = tid >> 6, lane = tid & 63;
  const _Float16* A = featT + (size_t)b * N_PIX * 640;
  int pr = p0 + wid * 16;
  f32x4 acc[8] = {};
  for (int kk = 0; kk < 20; ++kk) {
    f16x8 af = ldnt(A, pr, 640, kk * 32, lane);
#pragma unroll
    for (int nn = 0; nn < 8; ++nn) {
      f16x8 bf = ldnt(wh, nn * 16, 640, kk * 32, lane);
      acc[nn] = mfma16(af, bf, acc[nn]);
    }
  }
  _Float16* O = oT + (size_t)b * N_PIX * 128;
#pragma unroll
  for (int nn = 0; nn < 8; ++nn) {
    int oc = nn * 16 + (lane & 15);
    float bb = bias[oc];
#pragma unroll
    for (int r = 0; r < 4; ++r) {
      int pix = pr + ((lane >> 4) << 2) + r;
      O[(size_t)pix * 128 + oc] = (_Float16)(acc[nn][r] + bb);
    }
  }
}

// ---------- v: 1x1 conv 512->512 + bias -> [b][c][pix] fp16 (channel-major) ----------
__global__ __launch_bounds__(256) void k_v(const _Float16* __restrict__ xT, const _Float16* __restrict__ wvh,
                                           const float* __restrict__ bv, _Float16* __restrict__ vv) {
  int b = blockIdx.z, oc0 = blockIdx.x * 64, p0 = blockIdx.y * 128;
  int tid = threadIdx.x, wid = tid >> 6, lane = tid & 63;
  const _Float16* Bm = xT + (size_t)b * N_PIX * C_IN;
  int or0 = oc0 + wid * 16;
  f32x4 acc[8] = {};
  for (int kk = 0; kk < 16; ++kk) {
    f16x8 af = ldnt(wvh, or0, C_IN, kk * 32, lane);
#pragma unroll
    for (int nn = 0; nn < 8; ++nn) {
      f16x8 bf = ldnt(Bm, p0 + nn * 16, C_IN, kk * 32, lane);
      acc[nn] = mfma16(af, bf, acc[nn]);
    }
  }
  _Float16* V = vv + (size_t)b * C_IN * N_PIX;
#pragma unroll
  for (int r = 0; r < 4; ++r) {
    int oc = or0 + ((lane >> 4) << 2) + r;
    float bb = bv[oc];
#pragma unroll
    for (int nn = 0; nn < 8; ++nn) {
      int pix = p0 + nn * 16 + (lane & 15);
      V[(size_t)oc * N_PIX + pix] = (_Float16)(acc[nn][r] + bb);
    }
  }
}

// ---------- pass 1: partial row max + sumexp over an m-eighth (S^T orientation) ----------
__global__ __launch_bounds__(256) void k_pass1(const _Float16* __restrict__ qT, const _Float16* __restrict__ kT,
                                               float* __restrict__ pmaxP, float* __restrict__ psumP) {
  int b = blockIdx.z, n0 = blockIdx.x * 64, mq = blockIdx.y;
  int tid = threadIdx.x, wid = tid >> 6, lane = tid & 63;
  const _Float16* Q = qT + (size_t)b * N_PIX * 128;
  const _Float16* K = kT + (size_t)b * N_PIX * 128;
  f16x8 qf[4];
#pragma unroll
  for (int kk = 0; kk < 4; ++kk) qf[kk] = ldnt(Q, n0 + wid * 16, 128, kk * 32, lane);
  float mx = -3.4e38f, sm = 0.f;
  for (int it = 0; it < 8; ++it) {
    int m0 = mq * 512 + it * 64;
#pragma unroll
    for (int mm = 0; mm < 4; ++mm) {
      f32x4 s = {};
#pragma unroll
      for (int kk = 0; kk < 4; ++kk) {
        f16x8 kf = ldnt(K, m0 + mm * 16, 128, kk * 32, lane);
        s = mfma16(kf, qf[kk], s);  // S^T: col = n (lane&15), rows = m
      }
      float vmax = fmaxf(fmaxf(s[0], s[1]), fmaxf(s[2], s[3]));
      float newm = fmaxf(mx, vmax);
      sm = sm * __expf(mx - newm) + __expf(s[0] - newm) + __expf(s[1] - newm) +
           __expf(s[2] - newm) + __expf(s[3] - newm);
      mx = newm;
    }
  }
  // combine lanes holding the same n (lane, lane^16, lane^32)
#pragma unroll
  for (int off = 16; off < 64; off <<= 1) {
    float mo = __shfl_xor(mx, off);
    float lo = __shfl_xor(sm, off);
    float mn = fmaxf(mx, mo);
    sm = sm * __expf(mx - mn) + lo * __expf(mo - mn);
    mx = mn;
  }
  if (lane < 16) {
    size_t idx = ((size_t)(b * 8 + mq)) * N_PIX + n0 + wid * 16 + lane;
    pmaxP[idx] = mx;
    psumP[idx] = sm;
  }
}

// ---------- combine 8 m-eighth partials -> rmax, rsum ----------
__global__ __launch_bounds__(256) void k_comb(const float* __restrict__ pmaxP, const float* __restrict__ psumP,
                                              float* __restrict__ rmax, float* __restrict__ rsum) {
  int i = blockIdx.x * 256 + threadIdx.x;  // 4*4096
  int b = i >> 12, n = i & 4095;
  float m = -3.4e38f, l = 0.f;
#pragma unroll
  for (int q = 0; q < 8; ++q) {
    size_t idx = ((size_t)(b * 8 + q)) * N_PIX + n;
    float mq = pmaxP[idx], lq = psumP[idx];
    float nm = fmaxf(m, mq);
    l = l * __expf(m - nm) + lq * __expf(mq - nm);
    m = nm;
  }
  rmax[(size_t)b * N_PIX + n] = m;
  rsum[(size_t)b * N_PIX + n] = l;
}

// ---------- pass 2: fused S^T recompute -> P -> PV -> y = x + gamma*O/sum ----------
// n-tile 32, m-tile 128/barrier, c-split 2, XOR-swizzled double-buffered P.
__global__ __launch_bounds__(256, 4) void k_pass2(const _Float16* __restrict__ qT, const _Float16* __restrict__ kT,
                                                  const _Float16* __restrict__ vv, const float* __restrict__ rmax,
                                                  const float* __restrict__ rsum, const float* __restrict__ x,
                                                  const float* __restrict__ gamma, float* __restrict__ out) {
  __shared__ _Float16 Pb[2][32 * 128];  // [buf][n][m], row = 256B, XOR-swizzled by (n&7)<<4
  int b = blockIdx.z, n0 = blockIdx.x * 32, c0 = blockIdx.y * 256;
  int tid = threadIdx.x, wid = tid >> 6, lane = tid & 63;
  int ns = wid & 1;   // phaseA n-sub (16 rows)
  int wm = wid >> 1;  // phaseA m-half (64 of 128)
  const _Float16* Q = qT + (size_t)b * N_PIX * 128;
  const _Float16* K = kT + (size_t)b * N_PIX * 128;
  const _Float16* V = vv + (size_t)b * C_IN * N_PIX;
  float g = gamma[0];
  f16x8 qf[4];
#pragma unroll
  for (int kk = 0; kk < 4; ++kk) qf[kk] = ldnt(Q, n0 + ns * 16, 128, kk * 32, lane);
  int n_local = ns * 16 + (lane & 15);
  float pmax = rmax[(size_t)b * N_PIX + n0 + n_local];
  f32x4 acc[4][2] = {};

  auto phaseA = [&](int it, int buf) {
    int m_base = it * 128 + wm * 64;
#pragma unroll
    for (int mm = 0; mm < 4; ++mm) {
      f32x4 s = {};
#pragma unroll
      for (int kk = 0; kk < 4; ++kk) {
        f16x8 kf = ldnt(K, m_base + mm * 16, 128, kk * 32, lane);
        s = mfma16(kf, qf[kk], s);  // S^T: col=n, rows=m
      }
      f16x4 pv;
#pragma unroll
      for (int r = 0; r < 4; ++r) pv[r] = (_Float16)__expf(s[r] - pmax);
      int m_local = wm * 64 + mm * 16 + ((lane >> 4) << 2);
      int mb = (m_local * 2) ^ ((n_local & 7) << 4);
      *(f16x4*)((char*)&Pb[buf][0] + n_local * 256 + mb) = pv;
    }
  };
  auto phaseB = [&](int it, int buf) {
#pragma unroll
    for (int k2 = 0; k2 < 4; ++k2) {
      int mb = (k2 * 64 + ((lane >> 4) << 4)) ^ ((lane & 7) << 4);
      f16x8 pb0 = *(const f16x8*)((char*)&Pb[buf][0] + (lane & 15) * 256 + mb);
      f16x8 pb1 = *(const f16x8*)((char*)&Pb[buf][0] + (16 + (lane & 15)) * 256 + mb);
#pragma unroll
      for (int cc = 0; cc < 4; ++cc) {
        f16x8 af = ldnt(V, c0 + wid * 64 + cc * 16, N_PIX, it * 128 + k2 * 32, lane);
        acc[cc][0] = mfma16(af, pb0, acc[cc][0]);
        acc[cc][1] = mfma16(af, pb1, acc[cc][1]);
      }
    }
  };

  phaseA(0, 0);
  __syncthreads();
  for (int it = 0; it < 31; ++it) {
    phaseA(it + 1, (it + 1) & 1);  // fill other buffer
    phaseB(it, it & 1);            // consume current buffer
    __syncthreads();
  }
  phaseB(31, 1);

  // epilogue: normalize by row sum, y = x + g*O
  float inv_s[2];
#pragma unroll
  for (int n2 = 0; n2 < 2; ++n2)
    inv_s[n2] = 1.f / rsum[(size_t)b * N_PIX + n0 + n2 * 16 + (lane & 15)];
#pragma unroll
  for (int cc = 0; cc < 4; ++cc) {
#pragma unroll
    for (int r = 0; r < 4; ++r) {
      int oc = c0 + wid * 64 + cc * 16 + ((lane >> 4) << 2) + r;
#pragma unroll
      for (int n2 = 0; n2 < 2; ++n2) {
        int pix = n0 + n2 * 16 + (lane & 15);
        size_t idx = ((size_t)(b * C_IN + oc)) * N_PIX + pix;
        out[idx] = fmaf(g * inv_s[n2], acc[cc][n2][r], x[idx]);
      }
    }
  }
}

extern "C" void kernel_launch(void* const* d_in, const int* in_sizes, int n_in,
                              void* d_out, int out_size, void* d_ws, size_t ws_size,
                              hipStream_t stream) {
  const float* x = (const float*)d_in[0];
  const float* wa1 = (const float*)d_in[1];
  const float* wa2 = (const float*)d_in[2];
  const float* wa3 = (const float*)d_in[3];
  const float* wa4 = (const float*)d_in[4];
  const float* wa5 = (const float*)d_in[5];
  const float* bnS = (const float*)d_in[6];
  const float* bnB = (const float*)d_in[7];
  const float* wq = (const float*)d_in[8];
  const float* bq = (const float*)d_in[9];
  const float* wk = (const float*)d_in[10];
  const float* bk = (const float*)d_in[11];
  const float* wv = (const float*)d_in[12];
  const float* bv = (const float*)d_in[13];
  const float* gamma = (const float*)d_in[14];

  char* ws = (char*)d_ws;
  size_t off = 0;
  auto alloc = [&](size_t bytes) -> char* {
    char* p = ws + off;
    off = (off + bytes + 255) & ~(size_t)255;
    return p;
  };
  _Float16* xT = (_Float16*)alloc((size_t)4 * 4096 * 512 * 2);
  _Float16* featT = (_Float16*)alloc((size_t)4 * 4096 * 640 * 2);
  _Float16* qT = (_Float16*)alloc((size_t)4 * 4096 * 128 * 2);
  _Float16* kT = (_Float16*)alloc((size_t)4 * 4096 * 128 * 2);
  _Float16* vvp = (_Float16*)alloc((size_t)4 * 512 * 4096 * 2);
  _Float16* w1h = (_Float16*)alloc((size_t)128 * 512 * 2);
  _Float16* wph = (_Float16*)alloc((size_t)3 * 9 * 128 * 512 * 2);
  _Float16* wqh = (_Float16*)alloc((size_t)128 * 640 * 2);
  _Float16* wkh = (_Float16*)alloc((size_t)128 * 640 * 2);
  _Float16* wvh = (_Float16*)alloc((size_t)512 * 512 * 2);
  float* meanv = (float*)alloc((size_t)4 * 512 * 4);
  _Float16* p5h = (_Float16*)alloc((size_t)4 * 128 * 2);
  float* rmax = (float*)alloc((size_t)4 * 4096 * 4);
  float* rsum = (float*)alloc((size_t)4 * 4096 * 4);
  float* pmaxP = (float*)alloc((size_t)4 * 8 * 4096 * 4);
  float* psumP = (float*)alloc((size_t)4 * 8 * 4096 * 4);
  if (off > ws_size) return;  // workspace too small -> fail loudly via wrong output

  float* out = (float*)d_out;

  // stage inputs
  hipLaunchKernelGGL(k_xT, dim3(128, 16, 4), dim3(256), 0, stream, x, xT);
  hipLaunchKernelGGL(k_f2h4, dim3(1920), dim3(256), 0, stream, wa1, w1h, 65536, wq, wqh, 81920, wk, wkh, 81920,
                     wv, wvh, 262144);
  hipLaunchKernelGGL(k_packw, dim3(6912), dim3(256), 0, stream, wa2, wa3, wa4, wph);
  // ASPP
  hipLaunchKernelGGL(k_mean, dim3(512, 4), dim3(256), 0, stream, x, meanv);
  hipLaunchKernelGGL(k_p5, dim3(4), dim3(128), 0, stream, wa5, meanv, bnS + 4 * 128, bnB + 4 * 128, p5h);
  hipLaunchKernelGGL(k_b5, dim3(8192), dim3(256), 0, stream, p5h, featT);
  hipLaunchKernelGGL(k_conv, dim3(64, 16), dim3(256), 0, stream, xT, w1h, wph, bnS, bnB, featT);
  // q, k, v
  hipLaunchKernelGGL(k_qk, dim3(64, 2, 4), dim3(256), 0, stream, featT, wqh, wkh, bq, bk, qT, kT);
  hipLaunchKernelGGL(k_v, dim3(8, 32, 4), dim3(256), 0, stream, xT, wvh, bv, vvp);
  // attention
  hipLaunchKernelGGL(k_pass1, dim3(64, 8, 4), dim3(256), 0, stream, qT, kT, pmaxP, psumP);
  hipLaunchKernelGGL(k_comb, dim3(64), dim3(256), 0, stream, pmaxP, psumP, rmax, rsum);
  hipLaunchKernelGGL(k_pass2, dim3(128, 2, 4), dim3(256), 0, stream, qT, kT, vvp, rmax, rsum, x, gamma, out);
}

// Round 5
// 560.247 us; speedup vs baseline: 2.1767x; 1.5127x over previous
//
#include <hip/hip_runtime.h>

typedef _Float16 f16x8 __attribute__((ext_vector_type(8)));
typedef _Float16 f16x4 __attribute__((ext_vector_type(4)));
typedef float f32x4 __attribute__((ext_vector_type(4)));

#define N_PIX 4096
#define C_IN  512
#define BN_INV 0.99999500003749969f  // 1/sqrt(1+1e-5)
#define CCH 64  // conv c-chunk (K per LDS stage)

#define GLOAD_LDS16(g, l)                                        \
  __builtin_amdgcn_global_load_lds(                              \
      (const __attribute__((address_space(1))) void*)(g),        \
      (__attribute__((address_space(3))) void*)(l), 16, 0, 0)

__device__ __forceinline__ f32x4 mfma16(f16x8 a, f16x8 b, f32x4 c) {
  return __builtin_amdgcn_mfma_f32_16x16x32_f16(a, b, c, 0, 0, 0);
}
// NT fragment load: row = base_row + (lane&15), 8 contiguous k at k0 + (lane>>4)*8
__device__ __forceinline__ f16x8 ldnt(const _Float16* base, int row, int ld, int k0, int lane) {
  return *(const f16x8*)(base + (size_t)(row + (lane & 15)) * ld + k0 + ((lane >> 4) << 3));
}

// ---------- x NCHW fp32 -> xT [b][pix][c] fp16 (LDS tile transpose) ----------
__global__ __launch_bounds__(256) void k_xT(const float* __restrict__ x, _Float16* __restrict__ xT) {
  __shared__ float t[32][33];
  int b = blockIdx.z, p0 = blockIdx.x * 32, c0 = blockIdx.y * 32;
  int tx = threadIdx.x & 31, ty = threadIdx.x >> 5;  // 32 x 8
  const float* xb = x + ((size_t)b * C_IN + c0) * N_PIX + p0;
  for (int i = 0; i < 32; i += 8) t[ty + i][tx] = xb[(size_t)(ty + i) * N_PIX + tx];
  __syncthreads();
  _Float16* o = xT + ((size_t)b * N_PIX + p0) * C_IN + c0;
  for (int i = 0; i < 32; i += 8) o[(size_t)(ty + i) * C_IN + tx] = (_Float16)t[tx][ty + i];
}

// ---------- fused fp32 -> fp16 for 4 weight tensors ----------
__global__ __launch_bounds__(256) void k_f2h4(const float* __restrict__ a, _Float16* __restrict__ oa, int na,
                                              const float* __restrict__ b_, _Float16* __restrict__ ob, int nb,
                                              const float* __restrict__ c, _Float16* __restrict__ oc, int nc,
                                              const float* __restrict__ d, _Float16* __restrict__ od, int nd) {
  int i = blockIdx.x * 256 + threadIdx.x;
  if (i < na) { oa[i] = (_Float16)a[i]; return; }
  i -= na;
  if (i < nb) { ob[i] = (_Float16)b_[i]; return; }
  i -= nb;
  if (i < nc) { oc[i] = (_Float16)c[i]; return; }
  i -= nc;
  if (i < nd) od[i] = (_Float16)d[i];
}

// ---------- pack 3x3 dilated conv weights: [conv][tap][oc][c] fp16 ----------
__global__ __launch_bounds__(256) void k_packw(const float* __restrict__ w2, const float* __restrict__ w3,
                                               const float* __restrict__ w4, _Float16* __restrict__ wp) {
  int idx = blockIdx.x * 256 + threadIdx.x;  // 3*9*128*512 = 1769472
  int conv = idx / 589824;
  int t1 = idx % 589824;
  int tap = t1 / 65536;
  int t2 = t1 % 65536;
  int oc = t2 / 512, c = t2 % 512;
  const float* w = (conv == 0) ? w2 : (conv == 1) ? w3 : w4;
  wp[idx] = (_Float16)w[(size_t)(oc * 512 + c) * 9 + tap];
}

// ---------- per (b,c) mean over pixels ----------
__global__ __launch_bounds__(256) void k_mean(const float* __restrict__ x, float* __restrict__ meanv) {
  int c = blockIdx.x, b = blockIdx.y;
  const float* p = x + ((size_t)b * C_IN + c) * N_PIX;
  float s = 0.f;
  for (int i = threadIdx.x; i < N_PIX; i += 256) s += p[i];
  for (int off = 32; off; off >>= 1) s += __shfl_down(s, off);
  __shared__ float ls[4];
  if ((threadIdx.x & 63) == 0) ls[threadIdx.x >> 6] = s;
  __syncthreads();
  if (threadIdx.x == 0) meanv[(size_t)b * C_IN + c] = (ls[0] + ls[1] + ls[2] + ls[3]) * (1.f / N_PIX);
}

// ---------- branch 5: 1x1 conv on pooled vector + BN + ReLU ----------
__global__ void k_p5(const float* __restrict__ w5, const float* __restrict__ meanv,
                     const float* __restrict__ bnS, const float* __restrict__ bnB, _Float16* __restrict__ p5h) {
  int b = blockIdx.x, oc = threadIdx.x;  // 128 threads
  const float* m = meanv + (size_t)b * C_IN;
  const float* w = w5 + (size_t)oc * C_IN;
  float s = 0.f;
  for (int c = 0; c < C_IN; ++c) s += w[c] * m[c];
  float v = fmaxf(s * bnS[oc] * BN_INV + bnB[oc], 0.f);
  p5h[b * 128 + oc] = (_Float16)v;
}

// ---------- broadcast b5 into featT channels [512,640) ----------
__global__ __launch_bounds__(256) void k_b5(const _Float16* __restrict__ p5h, _Float16* __restrict__ featT) {
  int i = blockIdx.x * 256 + threadIdx.x;  // 4*4096*128
  int oc = i & 127, p = (i >> 7) & 4095, b = i >> 19;
  featT[((size_t)b * N_PIX + p) * 640 + 512 + oc] = p5h[b * 128 + oc];
}

// ---------- unified ASPP conv: LDS-staged implicit GEMM ----------
__global__ __launch_bounds__(256, 4) void k_conv(const _Float16* __restrict__ xT, const _Float16* __restrict__ w1h,
                                                 const _Float16* __restrict__ wph, const float* __restrict__ bnS,
                                                 const float* __restrict__ bnB, _Float16* __restrict__ featT) {
  __shared__ _Float16 Ap[3 * 76 * CCH];  // 29184 B
  int y = blockIdx.x;
  int tb = blockIdx.y;
  int task = tb >> 2, b = tb & 3;
  int tid = threadIdx.x, wid = tid >> 6, lane = tid & 63;
  int dil = (task == 0) ? 0 : (task == 1) ? 2 : (task == 2) ? 3 : 6;
  int ntap = task ? 9 : 1;
  int nrow = task ? 3 : 1;
  const _Float16* wt0 = task ? wph + (size_t)(task - 1) * 9 * 128 * C_IN : w1h;
  f32x4 acc[4][2] = {};

  for (int cc = 0; cc < C_IN / CCH; ++cc) {
    int c0 = cc * CCH;
    __syncthreads();  // previous chunk's compute done reading LDS
    if (dil) {
      int nz = nrow * 2 * dil * (CCH / 8);
      for (int i = tid; i < nz; i += 256) {
        int cv = (i & (CCH / 8 - 1)) * 8;
        int t2 = i / (CCH / 8);
        int colh = t2 % (2 * dil);
        int r = t2 / (2 * dil);
        int col = (colh < dil) ? colh : 64 + colh;
        int ba = (((r * 76 + col) * CCH + cv) * 2) ^ ((col & 7) << 4);
        *(f16x8*)((char*)Ap + ba) = (f16x8){};
      }
    }
    int nf = nrow * 64 * (CCH / 8);
    for (int i = tid; i < nf; i += 256) {
      int cv = (i & (CCH / 8 - 1)) * 8;
      int t2 = i / (CCH / 8);
      int px = t2 & 63;
      int r = t2 >> 6;
      int ry = y + (r - 1) * dil;
      f16x8 v = {};
      if ((unsigned)ry < 64u)
        v = *(const f16x8*)(xT + ((size_t)b * N_PIX + ry * 64 + px) * C_IN + c0 + cv);
      int col = dil + px;
      int ba = (((r * 76 + col) * CCH + cv) * 2) ^ ((col & 7) << 4);
      *(f16x8*)((char*)Ap + ba) = v;
    }
    __syncthreads();
    for (int tap = 0; tap < ntap; ++tap) {
      int rsel = tap / 3;
      int dx = (tap % 3 - 1) * dil;
      const _Float16* wt = wt0 + (size_t)tap * 128 * C_IN;
#pragma unroll
      for (int k = 0; k < CCH / 32; ++k) {
        f16x8 wf0 = ldnt(wt, wid * 32, C_IN, c0 + k * 32, lane);
        f16x8 wf1 = ldnt(wt, wid * 32 + 16, C_IN, c0 + k * 32, lane);
        f16x8 af[4];
#pragma unroll
        for (int m = 0; m < 4; ++m) {
          int col = dil + dx + m * 16 + (lane & 15);
          int ch = k * 32 + ((lane >> 4) << 3);
          int ba = (((rsel * 76 + col) * CCH + ch) * 2) ^ ((col & 7) << 4);
          af[m] = *(const f16x8*)((char*)Ap + ba);
        }
#pragma unroll
        for (int m = 0; m < 4; ++m) {
          acc[m][0] = mfma16(af[m], wf0, acc[m][0]);
          acc[m][1] = mfma16(af[m], wf1, acc[m][1]);
        }
      }
    }
  }
  int brOff = task * 128;
  _Float16* F = featT + (size_t)b * N_PIX * 640;
#pragma unroll
  for (int n = 0; n < 2; ++n) {
    int oc = wid * 32 + n * 16 + (lane & 15);
    float inv = bnS[brOff + oc] * BN_INV, bs = bnB[brOff + oc];
#pragma unroll
    for (int m = 0; m < 4; ++m) {
#pragma unroll
      for (int r = 0; r < 4; ++r) {
        int pix = y * 64 + m * 16 + ((lane >> 4) << 2) + r;
        F[(size_t)pix * 640 + brOff + oc] = (_Float16)fmaxf(acc[m][n][r] * inv + bs, 0.f);
      }
    }
  }
}

// ---------- q & k in one dispatch: 1x1 conv 640->128 + bias -> [b][pix][128] fp16 ----------
__global__ __launch_bounds__(256) void k_qk(const _Float16* __restrict__ featT, const _Float16* __restrict__ wqh,
                                            const _Float16* __restrict__ wkh, const float* __restrict__ bq,
                                            const float* __restrict__ bk, _Float16* __restrict__ qT,
                                            _Float16* __restrict__ kT) {
  int b = blockIdx.z, which = blockIdx.y, p0 = blockIdx.x * 64;
  const _Float16* wh = which ? wkh : wqh;
  const float* bias = which ? bk : bq;
  _Float16* oT = which ? kT : qT;
  int tid = threadIdx.x, wid = tid >> 6, lane = tid & 63;
  const _Float16* A = featT + (size_t)b * N_PIX * 640;
  int pr = p0 + wid * 16;
  f32x4 acc[8] = {};
  for (int kk = 0; kk < 20; ++kk) {
    f16x8 af = ldnt(A, pr, 640, kk * 32, lane);
#pragma unroll
    for (int nn = 0; nn < 8; ++nn) {
      f16x8 bf = ldnt(wh, nn * 16, 640, kk * 32, lane);
      acc[nn] = mfma16(af, bf, acc[nn]);
    }
  }
  _Float16* O = oT + (size_t)b * N_PIX * 128;
#pragma unroll
  for (int nn = 0; nn < 8; ++nn) {
    int oc = nn * 16 + (lane & 15);
    float bb = bias[oc];
#pragma unroll
    for (int r = 0; r < 4; ++r) {
      int pix = pr + ((lane >> 4) << 2) + r;
      O[(size_t)pix * 128 + oc] = (_Float16)(acc[nn][r] + bb);
    }
  }
}

// ---------- v: 1x1 conv 512->512 + bias -> [b][c][pix] fp16 (channel-major) ----------
__global__ __launch_bounds__(256) void k_v(const _Float16* __restrict__ xT, const _Float16* __restrict__ wvh,
                                           const float* __restrict__ bv, _Float16* __restrict__ vv) {
  int b = blockIdx.z, oc0 = blockIdx.x * 64, p0 = blockIdx.y * 128;
  int tid = threadIdx.x, wid = tid >> 6, lane = tid & 63;
  const _Float16* Bm = xT + (size_t)b * N_PIX * C_IN;
  int or0 = oc0 + wid * 16;
  f32x4 acc[8] = {};
  for (int kk = 0; kk < 16; ++kk) {
    f16x8 af = ldnt(wvh, or0, C_IN, kk * 32, lane);
#pragma unroll
    for (int nn = 0; nn < 8; ++nn) {
      f16x8 bf = ldnt(Bm, p0 + nn * 16, C_IN, kk * 32, lane);
      acc[nn] = mfma16(af, bf, acc[nn]);
    }
  }
  _Float16* V = vv + (size_t)b * C_IN * N_PIX;
#pragma unroll
  for (int r = 0; r < 4; ++r) {
    int oc = or0 + ((lane >> 4) << 2) + r;
    float bb = bv[oc];
#pragma unroll
    for (int nn = 0; nn < 8; ++nn) {
      int pix = p0 + nn * 16 + (lane & 15);
      V[(size_t)oc * N_PIX + pix] = (_Float16)(acc[nn][r] + bb);
    }
  }
}

// ---------- pass 1: partial row max + sumexp over an m-eighth (S^T orientation) ----------
__global__ __launch_bounds__(256) void k_pass1(const _Float16* __restrict__ qT, const _Float16* __restrict__ kT,
                                               float* __restrict__ pmaxP, float* __restrict__ psumP) {
  int b = blockIdx.z, n0 = blockIdx.x * 64, mq = blockIdx.y;
  int tid = threadIdx.x, wid = tid >> 6, lane = tid & 63;
  const _Float16* Q = qT + (size_t)b * N_PIX * 128;
  const _Float16* K = kT + (size_t)b * N_PIX * 128;
  f16x8 qf[4];
#pragma unroll
  for (int kk = 0; kk < 4; ++kk) qf[kk] = ldnt(Q, n0 + wid * 16, 128, kk * 32, lane);
  float mx = -3.4e38f, sm = 0.f;
  for (int it = 0; it < 8; ++it) {
    int m0 = mq * 512 + it * 64;
#pragma unroll
    for (int mm = 0; mm < 4; ++mm) {
      f32x4 s = {};
#pragma unroll
      for (int kk = 0; kk < 4; ++kk) {
        f16x8 kf = ldnt(K, m0 + mm * 16, 128, kk * 32, lane);
        s = mfma16(kf, qf[kk], s);  // S^T: col = n (lane&15), rows = m
      }
      float vmax = fmaxf(fmaxf(s[0], s[1]), fmaxf(s[2], s[3]));
      float newm = fmaxf(mx, vmax);
      sm = sm * __expf(mx - newm) + __expf(s[0] - newm) + __expf(s[1] - newm) +
           __expf(s[2] - newm) + __expf(s[3] - newm);
      mx = newm;
    }
  }
#pragma unroll
  for (int off = 16; off < 64; off <<= 1) {
    float mo = __shfl_xor(mx, off);
    float lo = __shfl_xor(sm, off);
    float mn = fmaxf(mx, mo);
    sm = sm * __expf(mx - mn) + lo * __expf(mo - mn);
    mx = mn;
  }
  if (lane < 16) {
    size_t idx = ((size_t)(b * 8 + mq)) * N_PIX + n0 + wid * 16 + lane;
    pmaxP[idx] = mx;
    psumP[idx] = sm;
  }
}

// ---------- combine 8 m-eighth partials -> rmax, rsum ----------
__global__ __launch_bounds__(256) void k_comb(const float* __restrict__ pmaxP, const float* __restrict__ psumP,
                                              float* __restrict__ rmax, float* __restrict__ rsum) {
  int i = blockIdx.x * 256 + threadIdx.x;  // 4*4096
  int b = i >> 12, n = i & 4095;
  float m = -3.4e38f, l = 0.f;
#pragma unroll
  for (int q = 0; q < 8; ++q) {
    size_t idx = ((size_t)(b * 8 + q)) * N_PIX + n;
    float mq = pmaxP[idx], lq = psumP[idx];
    float nm = fmaxf(m, mq);
    l = l * __expf(m - nm) + lq * __expf(mq - nm);
    m = nm;
  }
  rmax[(size_t)b * N_PIX + n] = m;
  rsum[(size_t)b * N_PIX + n] = l;
}

// ---------- pass 2: fused S^T recompute -> P -> PV -> y = x + gamma*O/sum ----------
// Block = 64 n x 512 c (8 waves x 64c), m-tile 128. K staged in LDS (double-buffered,
// global_load_lds w=16, XOR-swizzled via pre-swizzled source). V direct from global.
// grid (64 n-tiles, 4 b) = 256 blocks = 1/CU.
__global__ __launch_bounds__(512, 2) void k_pass2(const _Float16* __restrict__ qT, const _Float16* __restrict__ kT,
                                                  const _Float16* __restrict__ vv, const float* __restrict__ rmax,
                                                  const float* __restrict__ rsum, const float* __restrict__ x,
                                                  const float* __restrict__ gamma, float* __restrict__ out) {
  __shared__ _Float16 Kb[2][128 * 128];  // 2 x 32KB, row = 256B, swizzled by (m&7)<<4
  __shared__ _Float16 P[64 * 128];       // 16KB, row = 256B, swizzled by (n&7)<<4
  int b = blockIdx.y, n0 = blockIdx.x * 64;
  int tid = threadIdx.x, wid = tid >> 6, lane = tid & 63;
  int ns = wid & 3;   // phaseA n-sub (16 rows of 64)
  int wm = wid >> 2;  // phaseA m-half (64 of 128)
  const _Float16* Q = qT + (size_t)b * N_PIX * 128;
  const _Float16* K = kT + (size_t)b * N_PIX * 128;
  const _Float16* V = vv + (size_t)b * C_IN * N_PIX;
  float g = gamma[0];
  f16x8 qf[4];
#pragma unroll
  for (int kk = 0; kk < 4; ++kk) qf[kk] = ldnt(Q, n0 + ns * 16, 128, kk * 32, lane);
  int n_local = ns * 16 + (lane & 15);
  float pmax = rmax[(size_t)b * N_PIX + n0 + n_local];
  f32x4 acc[4][4] = {};  // [cc][nn]

  // stage K-tile `it` into Kb[buf]: linear LDS dest, inverse-swizzled global source
  auto stageK = [&](int it, int buf) {
    const _Float16* src = K + (size_t)it * 128 * 128;
    int r = wid * 16 + (lane >> 4);  // + i*4 below
    int cs = (lane & 15) << 4;       // byte slot within 256B row
#pragma unroll
    for (int i = 0; i < 4; ++i) {
      int rr = r + i * 4;
      const char* gp = (const char*)(src + (size_t)rr * 128) + (cs ^ ((rr & 7) << 4));
      char* lp = (char*)&Kb[buf][0] + (size_t)(wid * 16 + i * 4) * 256;
      GLOAD_LDS16(gp, lp);
    }
  };

  auto phaseA = [&](int it, int kbuf) {
    const char* kb = (const char*)&Kb[kbuf][0];
#pragma unroll
    for (int mm = 0; mm < 4; ++mm) {
      int row = wm * 64 + mm * 16 + (lane & 15);
      int kboff = (lane >> 4) << 4;
      f32x4 s = {};
#pragma unroll
      for (int kk = 0; kk < 4; ++kk) {
        f16x8 kf = *(const f16x8*)(kb + (size_t)row * 256 + ((kk * 64 + kboff) ^ ((row & 7) << 4)));
        s = mfma16(kf, qf[kk], s);  // S^T: col=n, rows=m
      }
      f16x4 pv;
#pragma unroll
      for (int r = 0; r < 4; ++r) pv[r] = (_Float16)__expf(s[r] - pmax);
      int m_local = wm * 64 + mm * 16 + ((lane >> 4) << 2);
      *(f16x4*)((char*)P + (size_t)n_local * 256 + ((m_local * 2) ^ ((n_local & 7) << 4))) = pv;
    }
  };

  auto phaseB = [&](int it) {
#pragma unroll
    for (int k2 = 0; k2 < 4; ++k2) {
      f16x8 pb[4];
#pragma unroll
      for (int nn = 0; nn < 4; ++nn) {
        int n = nn * 16 + (lane & 15);
        int mbyte = k2 * 64 + ((lane >> 4) << 4);
        pb[nn] = *(const f16x8*)((char*)P + (size_t)n * 256 + (mbyte ^ ((n & 7) << 4)));
      }
#pragma unroll
      for (int cc = 0; cc < 4; ++cc) {
        f16x8 af = ldnt(V, wid * 64 + cc * 16, N_PIX, it * 128 + k2 * 32, lane);
#pragma unroll
        for (int nn = 0; nn < 4; ++nn) acc[cc][nn] = mfma16(af, pb[nn], acc[cc][nn]);
      }
    }
  };

  stageK(0, 0);
  __syncthreads();
  for (int it = 0; it < 32; ++it) {
    if (it < 31) stageK(it + 1, (it + 1) & 1);  // async prefetch next K-tile
    phaseA(it, it & 1);
    __syncthreads();  // P ready (and prefetch drained by compiler vmcnt)
    phaseB(it);
    __syncthreads();  // P/Kb safe to overwrite
  }

  // epilogue: normalize by row sum, y = x + g*O
  float inv_s[4];
#pragma unroll
  for (int nn = 0; nn < 4; ++nn)
    inv_s[nn] = 1.f / rsum[(size_t)b * N_PIX + n0 + nn * 16 + (lane & 15)];
#pragma unroll
  for (int cc = 0; cc < 4; ++cc) {
#pragma unroll
    for (int r = 0; r < 4; ++r) {
      int oc = wid * 64 + cc * 16 + ((lane >> 4) << 2) + r;
#pragma unroll
      for (int nn = 0; nn < 4; ++nn) {
        int pix = n0 + nn * 16 + (lane & 15);
        size_t idx = ((size_t)(b * C_IN + oc)) * N_PIX + pix;
        out[idx] = fmaf(g * inv_s[nn], acc[cc][nn][r], x[idx]);
      }
    }
  }
}

extern "C" void kernel_launch(void* const* d_in, const int* in_sizes, int n_in,
                              void* d_out, int out_size, void* d_ws, size_t ws_size,
                              hipStream_t stream) {
  const float* x = (const float*)d_in[0];
  const float* wa1 = (const float*)d_in[1];
  const float* wa2 = (const float*)d_in[2];
  const float* wa3 = (const float*)d_in[3];
  const float* wa4 = (const float*)d_in[4];
  const float* wa5 = (const float*)d_in[5];
  const float* bnS = (const float*)d_in[6];
  const float* bnB = (const float*)d_in[7];
  const float* wq = (const float*)d_in[8];
  const float* bq = (const float*)d_in[9];
  const float* wk = (const float*)d_in[10];
  const float* bk = (const float*)d_in[11];
  const float* wv = (const float*)d_in[12];
  const float* bv = (const float*)d_in[13];
  const float* gamma = (const float*)d_in[14];

  char* ws = (char*)d_ws;
  size_t off = 0;
  auto alloc = [&](size_t bytes) -> char* {
    char* p = ws + off;
    off = (off + bytes + 255) & ~(size_t)255;
    return p;
  };
  _Float16* xT = (_Float16*)alloc((size_t)4 * 4096 * 512 * 2);
  _Float16* featT = (_Float16*)alloc((size_t)4 * 4096 * 640 * 2);
  _Float16* qT = (_Float16*)alloc((size_t)4 * 4096 * 128 * 2);
  _Float16* kT = (_Float16*)alloc((size_t)4 * 4096 * 128 * 2);
  _Float16* vvp = (_Float16*)alloc((size_t)4 * 512 * 4096 * 2);
  _Float16* w1h = (_Float16*)alloc((size_t)128 * 512 * 2);
  _Float16* wph = (_Float16*)alloc((size_t)3 * 9 * 128 * 512 * 2);
  _Float16* wqh = (_Float16*)alloc((size_t)128 * 640 * 2);
  _Float16* wkh = (_Float16*)alloc((size_t)128 * 640 * 2);
  _Float16* wvh = (_Float16*)alloc((size_t)512 * 512 * 2);
  float* meanv = (float*)alloc((size_t)4 * 512 * 4);
  _Float16* p5h = (_Float16*)alloc((size_t)4 * 128 * 2);
  float* rmax = (float*)alloc((size_t)4 * 4096 * 4);
  float* rsum = (float*)alloc((size_t)4 * 4096 * 4);
  float* pmaxP = (float*)alloc((size_t)4 * 8 * 4096 * 4);
  float* psumP = (float*)alloc((size_t)4 * 8 * 4096 * 4);
  if (off > ws_size) return;  // workspace too small -> fail loudly via wrong output

  float* out = (float*)d_out;

  // stage inputs
  hipLaunchKernelGGL(k_xT, dim3(128, 16, 4), dim3(256), 0, stream, x, xT);
  hipLaunchKernelGGL(k_f2h4, dim3(1920), dim3(256), 0, stream, wa1, w1h, 65536, wq, wqh, 81920, wk, wkh, 81920,
                     wv, wvh, 262144);
  hipLaunchKernelGGL(k_packw, dim3(6912), dim3(256), 0, stream, wa2, wa3, wa4, wph);
  // ASPP
  hipLaunchKernelGGL(k_mean, dim3(512, 4), dim3(256), 0, stream, x, meanv);
  hipLaunchKernelGGL(k_p5, dim3(4), dim3(128), 0, stream, wa5, meanv, bnS + 4 * 128, bnB + 4 * 128, p5h);
  hipLaunchKernelGGL(k_b5, dim3(8192), dim3(256), 0, stream, p5h, featT);
  hipLaunchKernelGGL(k_conv, dim3(64, 16), dim3(256), 0, stream, xT, w1h, wph, bnS, bnB, featT);
  // q, k, v
  hipLaunchKernelGGL(k_qk, dim3(64, 2, 4), dim3(256), 0, stream, featT, wqh, wkh, bq, bk, qT, kT);
  hipLaunchKernelGGL(k_v, dim3(8, 32, 4), dim3(256), 0, stream, xT, wvh, bv, vvp);
  // attention
  hipLaunchKernelGGL(k_pass1, dim3(64, 8, 4), dim3(256), 0, stream, qT, kT, pmaxP, psumP);
  hipLaunchKernelGGL(k_comb, dim3(64), dim3(256), 0, stream, pmaxP, psumP, rmax, rsum);
  hipLaunchKernelGGL(k_pass2, dim3(64, 4), dim3(512), 0, stream, qT, kT, vvp, rmax, rsum, x, gamma, out);
}